// Round 1
// baseline (286.755 us; speedup 1.0000x reference)
//
#include <hip/hip_runtime.h>

// Problem constants: x is (B=16, C=3, H=512, W=512) float32.
#define BC   48     // B*C
#define CNUM 3
#define HF   512
#define WF   512
#define HH   256    // H/2
#define WH   256    // W/2
#define TILE 16

__device__ __forceinline__ float4 mix13(const float4 a, const float4 b) {
    // 0.25*a + 0.75*b
    float4 r;
    r.x = fmaf(0.25f, a.x, 0.75f * b.x);
    r.y = fmaf(0.25f, a.y, 0.75f * b.y);
    r.z = fmaf(0.25f, a.z, 0.75f * b.z);
    r.w = fmaf(0.25f, a.w, 0.75f * b.w);
    return r;
}

__device__ __forceinline__ float4 mix31(const float4 a, const float4 b) {
    // 0.75*a + 0.25*b
    float4 r;
    r.x = fmaf(0.75f, a.x, 0.25f * b.x);
    r.y = fmaf(0.75f, a.y, 0.25f * b.y);
    r.z = fmaf(0.75f, a.z, 0.25f * b.z);
    r.w = fmaf(0.75f, a.w, 0.25f * b.w);
    return r;
}

__device__ __forceinline__ void store2(float* p, float a, float b) {
    float2 v; v.x = a; v.y = b;
    *reinterpret_cast<float2*>(p) = v;
}

__global__ __launch_bounds__(256) void wavelet_kernel(const float* __restrict__ x,
                                                      float* __restrict__ out) {
    // 18x18 float4 coefficient tile (LL,LH,HL,HH), +1 col pad for bank spread
    __shared__ float4 coef[TILE + 2][TILE + 3];

    const int tx = threadIdx.x;
    const int ty = threadIdx.y;
    const int k0 = blockIdx.y * TILE;   // Haar-grid row origin
    const int l0 = blockIdx.x * TILE;   // Haar-grid col origin
    const int bc = blockIdx.z;          // fused (b,c)
    const int b  = bc / CNUM;
    const int c  = bc - b * CNUM;

    const float* __restrict__ xin = x + (size_t)bc * (HF * WF);

    // ---- Phase 1: fill coefficient tile with clamped halo ----
    const int t = ty * TILE + tx;
    for (int i = t; i < (TILE + 2) * (TILE + 2); i += 256) {
        const int ry = i / (TILE + 2);
        const int rx = i - ry * (TILE + 2);
        int k = k0 + ry - 1; k = k < 0 ? 0 : (k > HH - 1 ? HH - 1 : k);
        int l = l0 + rx - 1; l = l < 0 ? 0 : (l > WH - 1 ? WH - 1 : l);
        const float* p = xin + (2 * k) * WF + 2 * l;
        const float2 top = *reinterpret_cast<const float2*>(p);
        const float2 bot = *reinterpret_cast<const float2*>(p + WF);
        const float a = top.x, bb = top.y, cc = bot.x, dd = bot.y;
        float4 v;
        v.x = (a + bb + cc + dd) * 0.5f;  // LL
        v.y = (a + bb - cc - dd) * 0.5f;  // LH
        v.z = (a - bb + cc - dd) * 0.5f;  // HL
        v.w = (a - bb - cc + dd) * 0.5f;  // HH
        coef[ry][rx] = v;
    }
    __syncthreads();

    // ---- Phase 2: separable bilinear upsample from 3x3 neighborhood ----
    const int k = k0 + ty;
    const int l = l0 + tx;

    const float4 c00 = coef[ty][tx],     c01 = coef[ty][tx + 1],     c02 = coef[ty][tx + 2];
    const float4 c10 = coef[ty + 1][tx], c11 = coef[ty + 1][tx + 1], c12 = coef[ty + 1][tx + 2];
    const float4 c20 = coef[ty + 2][tx], c21 = coef[ty + 2][tx + 1], c22 = coef[ty + 2][tx + 2];

    // horizontal interpolation per coeff row: h0 -> output col 2l, h1 -> 2l+1
    const float4 h0r0 = mix13(c00, c01), h1r0 = mix31(c01, c02);
    const float4 h0r1 = mix13(c10, c11), h1r1 = mix31(c11, c12);
    const float4 h0r2 = mix13(c20, c21), h1r2 = mix31(c21, c22);

    // vertical: even output row uses (k-1,k)=(r0,r1) w (.25,.75); odd uses (k,k+1)=(r1,r2) w (.75,.25)
    const float4 v00 = mix13(h0r0, h0r1);  // (2k,   2l)
    const float4 v01 = mix13(h1r0, h1r1);  // (2k,   2l+1)
    const float4 v10 = mix31(h0r1, h0r2);  // (2k+1, 2l)
    const float4 v11 = mix31(h1r1, h1r2);  // (2k+1, 2l+1)

    const int y0 = 2 * k;
    const int x0 = 2 * l;
    float* __restrict__ outp = out + (size_t)(b * 15 + c * 5) * HF * WF;

    // band 0: identity copy of x (L1/L2-hot re-read)
    {
        const float* p = xin + y0 * WF + x0;
        const float2 t0 = *reinterpret_cast<const float2*>(p);
        const float2 t1 = *reinterpret_cast<const float2*>(p + WF);
        store2(outp + (size_t)y0 * WF + x0, t0.x, t0.y);
        store2(outp + (size_t)(y0 + 1) * WF + x0, t1.x, t1.y);
    }
    // bands 1..4: LL, LH, HL, HH upsampled
    {
        float* o = outp + (size_t)1 * HF * WF;
        store2(o + (size_t)y0 * WF + x0, v00.x, v01.x);
        store2(o + (size_t)(y0 + 1) * WF + x0, v10.x, v11.x);
    }
    {
        float* o = outp + (size_t)2 * HF * WF;
        store2(o + (size_t)y0 * WF + x0, v00.y, v01.y);
        store2(o + (size_t)(y0 + 1) * WF + x0, v10.y, v11.y);
    }
    {
        float* o = outp + (size_t)3 * HF * WF;
        store2(o + (size_t)y0 * WF + x0, v00.z, v01.z);
        store2(o + (size_t)(y0 + 1) * WF + x0, v10.z, v11.z);
    }
    {
        float* o = outp + (size_t)4 * HF * WF;
        store2(o + (size_t)y0 * WF + x0, v00.w, v01.w);
        store2(o + (size_t)(y0 + 1) * WF + x0, v10.w, v11.w);
    }
}

extern "C" void kernel_launch(void* const* d_in, const int* in_sizes, int n_in,
                              void* d_out, int out_size, void* d_ws, size_t ws_size,
                              hipStream_t stream) {
    const float* x = (const float*)d_in[0];
    float* out = (float*)d_out;
    dim3 grid(WH / TILE, HH / TILE, BC);   // 16 x 16 x 48 blocks
    dim3 block(TILE, TILE);                // 256 threads
    hipLaunchKernelGGL(wavelet_kernel, grid, block, 0, stream, x, out);
}

// Round 2
// 280.041 us; speedup vs baseline: 1.0240x; 1.0240x over previous
//
#include <hip/hip_runtime.h>

// x: (B=16, C=3, H=512, W=512) float32 -> out: (16, 15, 512, 512) float32
#define BC   48
#define HF   512
#define WF   512
#define HH   256
#define WH   256
#define TK   16     // Haar-grid rows per block
#define TL   32     // Haar-grid cols per block
#define HW   (HF * WF)

typedef float v4 __attribute__((ext_vector_type(4)));
typedef float v2 __attribute__((ext_vector_type(2)));

__global__ __launch_bounds__(256) void wavelet_kernel(const float* __restrict__ x,
                                                      float* __restrict__ out) {
    // 18 x 34 coefficient tile (LL,LH,HL,HH packed in v4), +1 col pad
    __shared__ v4 coef[TK + 2][TL + 3];

    const int tx = threadIdx.x;          // 0..15
    const int ty = threadIdx.y;          // 0..15
    const int k0 = blockIdx.y * TK;
    const int l0 = blockIdx.x * TL;
    const int bc = blockIdx.z;

    const float* __restrict__ xin = x + (size_t)bc * HW;

    // ---- Phase 1: Haar coefficients into LDS, clamped halo of 1 ----
    const int t = ty * 16 + tx;
    for (int i = t; i < (TK + 2) * (TL + 2); i += 256) {
        const int ry = i / (TL + 2);
        const int rx = i - ry * (TL + 2);
        int k = k0 + ry - 1; k = k < 0 ? 0 : (k > HH - 1 ? HH - 1 : k);
        int l = l0 + rx - 1; l = l < 0 ? 0 : (l > WH - 1 ? WH - 1 : l);
        const float* p = xin + (size_t)(2 * k) * WF + 2 * l;
        const v2 top = *reinterpret_cast<const v2*>(p);
        const v2 bot = *reinterpret_cast<const v2*>(p + WF);
        const float a = top.x, b = top.y, c = bot.x, d = bot.y;
        v4 v;
        v.x = (a + b + c + d) * 0.5f;  // LL
        v.y = (a + b - c - d) * 0.5f;  // LH
        v.z = (a - b + c - d) * 0.5f;  // HL
        v.w = (a - b - c + d) * 0.5f;  // HH
        coef[ry][rx] = v;
    }
    __syncthreads();

    // ---- Phase 2: each thread -> 4 output cols x 2 output rows, all 5 bands ----
    // coeff tile cols needed: 2tx .. 2tx+3 (abs cols l0+2tx-1 .. l0+2tx+2)
    // coeff tile rows needed: ty .. ty+2   (abs rows k0+ty-1 .. k0+ty+1)
    v4 hr[3][4];
#pragma unroll
    for (int r = 0; r < 3; ++r) {
        const v4 A = coef[ty + r][2 * tx];
        const v4 B = coef[ty + r][2 * tx + 1];
        const v4 C = coef[ty + r][2 * tx + 2];
        const v4 D = coef[ty + r][2 * tx + 3];
        hr[r][0] = A * 0.25f + B * 0.75f;   // out col 4tx+0 (even)
        hr[r][1] = B * 0.75f + C * 0.25f;   // out col 4tx+1 (odd)
        hr[r][2] = B * 0.25f + C * 0.75f;   // out col 4tx+2 (even)
        hr[r][3] = C * 0.75f + D * 0.25f;   // out col 4tx+3 (odd)
    }
    v4 ve[4], vo[4];
#pragma unroll
    for (int j = 0; j < 4; ++j) {
        ve[j] = hr[0][j] * 0.25f + hr[1][j] * 0.75f;  // even out row 2k
        vo[j] = hr[1][j] * 0.75f + hr[2][j] * 0.25f;  // odd out row 2k+1
    }

    const int y0 = 2 * (k0 + ty);
    const int x0 = 2 * l0 + 4 * tx;            // multiple of 4 -> 16B aligned
    float* __restrict__ outp = out + (size_t)bc * 5 * HW;

    // band 0: identity copy of x (L1-hot from phase 1)
    {
        const v4 t0 = *reinterpret_cast<const v4*>(xin + (size_t)y0 * WF + x0);
        const v4 t1 = *reinterpret_cast<const v4*>(xin + (size_t)(y0 + 1) * WF + x0);
        __builtin_nontemporal_store(t0, reinterpret_cast<v4*>(outp + (size_t)y0 * WF + x0));
        __builtin_nontemporal_store(t1, reinterpret_cast<v4*>(outp + (size_t)(y0 + 1) * WF + x0));
    }
    // bands 1..4: gather per-band across the 4 columns and store float4 rows
#define STORE_BAND(BIDX, COMP)                                                         \
    {                                                                                  \
        v4 e, o;                                                                       \
        e.x = ve[0].COMP; e.y = ve[1].COMP; e.z = ve[2].COMP; e.w = ve[3].COMP;        \
        o.x = vo[0].COMP; o.y = vo[1].COMP; o.z = vo[2].COMP; o.w = vo[3].COMP;        \
        float* ob = outp + (size_t)BIDX * HW;                                          \
        __builtin_nontemporal_store(e, reinterpret_cast<v4*>(ob + (size_t)y0 * WF + x0)); \
        __builtin_nontemporal_store(o, reinterpret_cast<v4*>(ob + (size_t)(y0 + 1) * WF + x0)); \
    }
    STORE_BAND(1, x)  // LL
    STORE_BAND(2, y)  // LH
    STORE_BAND(3, z)  // HL
    STORE_BAND(4, w)  // HH
#undef STORE_BAND
}

extern "C" void kernel_launch(void* const* d_in, const int* in_sizes, int n_in,
                              void* d_out, int out_size, void* d_ws, size_t ws_size,
                              hipStream_t stream) {
    const float* x = (const float*)d_in[0];
    float* out = (float*)d_out;
    dim3 grid(WH / TL, HH / TK, BC);   // 8 x 16 x 48 = 6144 blocks
    dim3 block(16, 16);                // 256 threads
    hipLaunchKernelGGL(wavelet_kernel, grid, block, 0, stream, x, out);
}

// Round 3
// 279.710 us; speedup vs baseline: 1.0252x; 1.0012x over previous
//
#include <hip/hip_runtime.h>

// x: (B=16, C=3, H=512, W=512) float32 -> out: (16, 15, 512, 512) float32
#define BC   48
#define HF   512
#define WF   512
#define HH   256
#define WH   256
#define TK   4      // Haar-grid rows per block (output rows = 8)
#define TL   128    // Haar-grid cols per block (output cols = 256 = 1KB)
#define HW   (HF * WF)

typedef float v4 __attribute__((ext_vector_type(4)));
typedef float v2 __attribute__((ext_vector_type(2)));

__global__ __launch_bounds__(256) void wavelet_kernel(const float* __restrict__ x,
                                                      float* __restrict__ out) {
    // Coefficient tile (LL,LH,HL,HH packed in v4), rows k0-1..k0+4 (6),
    // cols l0-1..l0+128 (130), split into even/odd column planes so that
    // phase-2 ds_read_b128 is lane-consecutive (conflict-free).
    // plane p, row r, slot s holds coef col (2s + p); LDS col c -> [c&1][.][c>>1]
    __shared__ v4 coef[2][TK + 2][TL / 2 + 1];   // 2*6*65*16B = 12.5 KB

    const int tx = threadIdx.x;          // 0..63 (one wave per ty)
    const int ty = threadIdx.y;          // 0..3
    const int k0 = blockIdx.y * TK;
    const int l0 = blockIdx.x * TL;
    const int bc = blockIdx.z;

    const float* __restrict__ xin = x + (size_t)bc * HW;

    // ---- Phase 1: Haar coefficients into LDS, clamped halo of 1 ----
    const int t = ty * 64 + tx;
    for (int i = t; i < (TK + 2) * (TL + 2); i += 256) {
        const int ry = i / (TL + 2);
        const int rx = i - ry * (TL + 2);
        int k = k0 + ry - 1; k = k < 0 ? 0 : (k > HH - 1 ? HH - 1 : k);
        int l = l0 + rx - 1; l = l < 0 ? 0 : (l > WH - 1 ? WH - 1 : l);
        const float* p = xin + (size_t)(2 * k) * WF + 2 * l;
        const v2 top = *reinterpret_cast<const v2*>(p);
        const v2 bot = *reinterpret_cast<const v2*>(p + WF);
        const float a = top.x, b = top.y, c = bot.x, d = bot.y;
        v4 v;
        v.x = (a + b + c + d) * 0.5f;  // LL
        v.y = (a + b - c - d) * 0.5f;  // LH
        v.z = (a - b + c - d) * 0.5f;  // HL
        v.w = (a - b - c + d) * 0.5f;  // HH
        coef[rx & 1][ry][rx >> 1] = v;
    }
    __syncthreads();

    // ---- Phase 2: thread -> 4 output cols x 2 output rows, all 5 bands ----
    // k = k0 + ty; needs coef rows ty..ty+2 (abs k-1..k+1)
    // out cols 4tx..4tx+3; needs LDS coef cols 2tx..2tx+3:
    //   A=even[tx], B=odd[tx], C=even[tx+1], D=odd[tx+1]
    v4 hr[3][4];
#pragma unroll
    for (int r = 0; r < 3; ++r) {
        const v4 A = coef[0][ty + r][tx];
        const v4 B = coef[1][ty + r][tx];
        const v4 C = coef[0][ty + r][tx + 1];
        const v4 D = coef[1][ty + r][tx + 1];
        hr[r][0] = A * 0.25f + B * 0.75f;   // out col 4tx+0 (even)
        hr[r][1] = B * 0.75f + C * 0.25f;   // out col 4tx+1 (odd)
        hr[r][2] = B * 0.25f + C * 0.75f;   // out col 4tx+2 (even)
        hr[r][3] = C * 0.75f + D * 0.25f;   // out col 4tx+3 (odd)
    }
    v4 ve[4], vo[4];
#pragma unroll
    for (int j = 0; j < 4; ++j) {
        ve[j] = hr[0][j] * 0.25f + hr[1][j] * 0.75f;  // even out row 2k
        vo[j] = hr[1][j] * 0.75f + hr[2][j] * 0.25f;  // odd out row 2k+1
    }

    const int y0 = 2 * (k0 + ty);
    const int x0 = 2 * l0 + 4 * tx;            // 16B aligned; wave covers 1KB run
    float* __restrict__ outp = out + (size_t)bc * 5 * HW;

    // band 0: identity copy of x (L1-hot from phase 1)
    {
        const v4 t0 = *reinterpret_cast<const v4*>(xin + (size_t)y0 * WF + x0);
        const v4 t1 = *reinterpret_cast<const v4*>(xin + (size_t)(y0 + 1) * WF + x0);
        __builtin_nontemporal_store(t0, reinterpret_cast<v4*>(outp + (size_t)y0 * WF + x0));
        __builtin_nontemporal_store(t1, reinterpret_cast<v4*>(outp + (size_t)(y0 + 1) * WF + x0));
    }
#define STORE_BAND(BIDX, COMP)                                                         \
    {                                                                                  \
        v4 e, o;                                                                       \
        e.x = ve[0].COMP; e.y = ve[1].COMP; e.z = ve[2].COMP; e.w = ve[3].COMP;        \
        o.x = vo[0].COMP; o.y = vo[1].COMP; o.z = vo[2].COMP; o.w = vo[3].COMP;        \
        float* ob = outp + (size_t)BIDX * HW;                                          \
        __builtin_nontemporal_store(e, reinterpret_cast<v4*>(ob + (size_t)y0 * WF + x0)); \
        __builtin_nontemporal_store(o, reinterpret_cast<v4*>(ob + (size_t)(y0 + 1) * WF + x0)); \
    }
    STORE_BAND(1, x)  // LL
    STORE_BAND(2, y)  // LH
    STORE_BAND(3, z)  // HL
    STORE_BAND(4, w)  // HH
#undef STORE_BAND
}

extern "C" void kernel_launch(void* const* d_in, const int* in_sizes, int n_in,
                              void* d_out, int out_size, void* d_ws, size_t ws_size,
                              hipStream_t stream) {
    const float* x = (const float*)d_in[0];
    float* out = (float*)d_out;
    dim3 grid(WH / TL, HH / TK, BC);   // 2 x 64 x 48 = 6144 blocks
    dim3 block(64, 4);                 // 256 threads; wave = one output row pair
    hipLaunchKernelGGL(wavelet_kernel, grid, block, 0, stream, x, out);
}